// Round 4
// baseline (330.559 us; speedup 1.0000x reference)
//
#include <hip/hip_runtime.h>
#include <math.h>

// Problem constants (reference: B=64, L=512, H=512, LOC_SIZE=100000)
constexpr int NB = 64;
constexpr int NL = 512;
constexpr int NH = 512;
#define EPSV 1e-9f

// Workspace layout (floats):
//   S   : 4 * NH * NB   (S_t[arr][h][b], arr = {ca, cb, da, db})
//   Vc  : NH * NB       (Vc_t[k][b])
//   Vd  : NH * NB       (Vd_t[k][b])
//   lg  : NB * NH       (logits[b][j] -- transposed for coalesced softmax)
// S/Vc/Vd/lg are FULLY written by their producer kernels (no memset, no atomics).

// ---------------------------------------------------------------------------
// K1: masked, coefficient-weighted gather-reduce over L. Atomic-free.
// grid = (NH/32, NB) = (16, 64) blocks, 256 threads.
// Thread (hi = tid&7, ls = tid>>3): h-range hc*32 + hi*4 .. +3, l stride 32.
// Gathers: 8 lanes x float4 = 128 B contiguous per row per l. Register
// accumulate, shuffle-reduce the 8 ls-groups per wave, LDS-combine the
// 4 waves, direct store (each S element owned by exactly one block).
// ---------------------------------------------------------------------------
__global__ __launch_bounds__(256) void k1_gather(
    const float* __restrict__ td_u, const float* __restrict__ td_l,
    const float* __restrict__ ld_u, const float* __restrict__ ld_l,
    const int* __restrict__ cur_loc, const int* __restrict__ loc_len,
    const float* __restrict__ locw, float* __restrict__ S)
{
    const int hc  = blockIdx.x;       // h-chunk: 32 h each
    const int b   = blockIdx.y;
    const int len = loc_len[b];
    const int tid = threadIdx.x;
    const int hi  = tid & 7;          // h-group (4 floats) within chunk
    const int ls  = tid >> 3;         // l-slice 0..31
    const int hbase = hc * 32 + hi * 4;

    float acc[4][4];
#pragma unroll
    for (int a = 0; a < 4; ++a)
#pragma unroll
        for (int e = 0; e < 4; ++e) acc[a][e] = 0.f;

#pragma unroll 4
    for (int l = ls; l < len; l += 32) {
        const int off = b * NL + l;
        const float tu = td_u[off], tl = td_l[off];
        const float lu = ld_u[off], ll = ld_l[off];
        const float rt = 1.f / (tu + tl + EPSV);
        const float rl = 1.f / (lu + ll + EPSV);
        const float a_ = tu * rt, b_ = tl * rt;
        const float c_ = lu * rl, d_ = ll * rl;
        const float w[4] = { c_ * a_, c_ * b_, d_ * a_, d_ * b_ };
        const int idx = cur_loc[off];
        const float4 x = *(const float4*)(locw + (size_t)idx * NH + hbase);
#pragma unroll
        for (int a = 0; a < 4; ++a) {
            acc[a][0] += w[a] * x.x;
            acc[a][1] += w[a] * x.y;
            acc[a][2] += w[a] * x.z;
            acc[a][3] += w[a] * x.w;
        }
    }

    // reduce the 8 ls-groups within each wave (lane stride 8)
#pragma unroll
    for (int a = 0; a < 4; ++a)
#pragma unroll
        for (int e = 0; e < 4; ++e) {
            float x = acc[a][e];
            x += __shfl_down(x, 32);
            x += __shfl_down(x, 16);
            x += __shfl_down(x, 8);
            acc[a][e] = x;
        }

    __shared__ float red[4][8][17];   // [wave][hi][v], padded vs bank conflicts
    const int wv = tid >> 6;
    if ((tid & 63) < 8) {
#pragma unroll
        for (int a = 0; a < 4; ++a)
#pragma unroll
            for (int e = 0; e < 4; ++e) red[wv][hi][a * 4 + e] = acc[a][e];
    }
    __syncthreads();

    if (tid < 128) {
        const int hi2 = tid & 7;
        const int v   = tid >> 3;     // 0..15
        const float s = red[0][hi2][v] + red[1][hi2][v]
                      + red[2][hi2][v] + red[3][hi2][v];
        const int a = v >> 2, e = v & 3;
        S[a * (NH * NB) + (hc * 32 + hi2 * 4 + e) * NB + b] = s;
    }
}

// ---------------------------------------------------------------------------
// K2: j-tiled x4. grid = NH/4 = 128 blocks, 256 threads.
// Block j0..j0+3: stage 4 rows of Wtu/Wtl in LDS (16 KB), loop h split
// across 4 waves (128 each), lane = b. 8 accumulators/lane. S read once
// per block -> total S traffic 64 MB (was 256 MB).
// ---------------------------------------------------------------------------
__global__ __launch_bounds__(256) void k2_vt(
    const float* __restrict__ Wtu, const float* __restrict__ Wtl,
    const float* __restrict__ S,
    float* __restrict__ Vc, float* __restrict__ Vd)
{
    const int j0  = blockIdx.x * 4;
    const int tid = threadIdx.x;

    __shared__ float wu_s[4][NH];
    __shared__ float wl_s[4][NH];
    __shared__ float comb[4][4][2][NB];   // [wave][j][vc/vd][lane]

    {   // rows j0..j0+3 are contiguous: 2048 floats = 512 float4 per matrix
        const float4* su = (const float4*)(Wtu + (size_t)j0 * NH);
        const float4* sl = (const float4*)(Wtl + (size_t)j0 * NH);
        float4* du = (float4*)&wu_s[0][0];
        float4* dl = (float4*)&wl_s[0][0];
        du[tid] = su[tid];  du[tid + 256] = su[tid + 256];
        dl[tid] = sl[tid];  dl[tid + 256] = sl[tid + 256];
    }
    __syncthreads();

    const int w    = tid >> 6;
    const int lane = tid & 63;
    const float* __restrict__ Sca = S;
    const float* __restrict__ Scb = S + NH * NB;
    const float* __restrict__ Sda = S + 2 * NH * NB;
    const float* __restrict__ Sdb = S + 3 * NH * NB;

    float vc[4] = {0.f, 0.f, 0.f, 0.f};
    float vd[4] = {0.f, 0.f, 0.f, 0.f};
    const int hbeg = w * 128;
#pragma unroll 4
    for (int h = hbeg; h < hbeg + 128; ++h) {
        const int o = h * NB + lane;
        const float sca = Sca[o], scb = Scb[o];
        const float sda = Sda[o], sdb = Sdb[o];
#pragma unroll
        for (int j = 0; j < 4; ++j) {
            const float wu = wu_s[j][h], wl = wl_s[j][h];
            vc[j] += wu * sca + wl * scb;
            vd[j] += wu * sda + wl * sdb;
        }
    }
#pragma unroll
    for (int j = 0; j < 4; ++j) {
        comb[w][j][0][lane] = vc[j];
        comb[w][j][1][lane] = vd[j];
    }
    __syncthreads();

    // 512 outputs, 2 per thread
#pragma unroll
    for (int t = tid; t < 512; t += 256) {
        const int j  = t >> 7;
        const int io = (t >> 6) & 1;
        const int ln = t & 63;
        const float v = comb[0][j][io][ln] + comb[1][j][io][ln]
                      + comb[2][j][io][ln] + comb[3][j][io][ln];
        if (io == 0) Vc[(j0 + j) * NB + ln] = v;
        else         Vd[(j0 + j) * NB + ln] = v;
    }
}

// ---------------------------------------------------------------------------
// K3: j-tiled x4, same structure as K2; usr[j] folded in; logits stored
// TRANSPOSED lg[b][j] so k4's reads coalesce.
// ---------------------------------------------------------------------------
__global__ __launch_bounds__(256) void k3_logits(
    const float* __restrict__ Wsu, const float* __restrict__ Wsl,
    const float* __restrict__ Wih, const float* __restrict__ h0p,
    const float* __restrict__ Vc, const float* __restrict__ Vd,
    float* __restrict__ lg)
{
    const int j0  = blockIdx.x * 4;
    const int tid = threadIdx.x;

    __shared__ float su_s[4][NH];
    __shared__ float sl_s[4][NH];
    __shared__ float ih_s[4][NH];
    __shared__ float h0_s[NH];
    __shared__ float comb[4][4][NB];      // [wave][j][lane]
    __shared__ float comb_u[4][4];        // [wave][j]

    {
        const float4* su = (const float4*)(Wsu + (size_t)j0 * NH);
        const float4* sl = (const float4*)(Wsl + (size_t)j0 * NH);
        const float4* ih = (const float4*)(Wih + (size_t)j0 * NH);
        float4* dsu = (float4*)&su_s[0][0];
        float4* dsl = (float4*)&sl_s[0][0];
        float4* dih = (float4*)&ih_s[0][0];
        dsu[tid] = su[tid];  dsu[tid + 256] = su[tid + 256];
        dsl[tid] = sl[tid];  dsl[tid + 256] = sl[tid + 256];
        dih[tid] = ih[tid];  dih[tid + 256] = ih[tid + 256];
        if (tid < 128) ((float4*)h0_s)[tid] = ((const float4*)h0p)[tid];
    }
    __syncthreads();

    const int w    = tid >> 6;
    const int lane = tid & 63;

    float s[4] = {0.f, 0.f, 0.f, 0.f};
    float u[4] = {0.f, 0.f, 0.f, 0.f};
    const int kbeg = w * 128;
#pragma unroll 4
    for (int k = kbeg; k < kbeg + 128; ++k) {
        const int o = k * NB + lane;
        const float vcv = Vc[o], vdv = Vd[o];
        const float h0v = h0_s[k];
#pragma unroll
        for (int j = 0; j < 4; ++j) {
            s[j] += su_s[j][k] * vcv + sl_s[j][k] * vdv;
            u[j] += ih_s[j][k] * h0v;
        }
    }
#pragma unroll
    for (int j = 0; j < 4; ++j) {
        comb[w][j][lane] = s[j];
        if (lane == 0) comb_u[w][j] = u[j];
    }
    __syncthreads();

    // transpose-store: thread t -> (b = t>>2, jj = t&3); 4 threads share a
    // 16 B contiguous chunk of lg[b][j0..j0+3]
    {
        const int b  = tid >> 2;
        const int jj = tid & 3;
        const float sv = comb[0][jj][b] + comb[1][jj][b]
                       + comb[2][jj][b] + comb[3][jj][b];
        const float uv = comb_u[0][jj] + comb_u[1][jj]
                       + comb_u[2][jj] + comb_u[3][jj];
        lg[b * NH + j0 + jj] = sv + uv;
    }
}

// ---------------------------------------------------------------------------
// K4: per-batch softmax over H. grid = NB, block = 512 (thread j).
// lg is [b][j] so reads/writes are fully coalesced.
// ---------------------------------------------------------------------------
__global__ __launch_bounds__(512) void k4_softmax(
    const float* __restrict__ lg, float* __restrict__ out)
{
    const int b = blockIdx.x;
    const int j = threadIdx.x;
    __shared__ float sd[512];

    const float v = lg[b * NH + j];
    sd[j] = v;
    __syncthreads();
    for (int s = 256; s > 0; s >>= 1) {
        if (j < s) sd[j] = fmaxf(sd[j], sd[j + s]);
        __syncthreads();
    }
    const float m = sd[0];
    __syncthreads();
    const float e = expf(v - m);
    sd[j] = e;
    __syncthreads();
    for (int s = 256; s > 0; s >>= 1) {
        if (j < s) sd[j] += sd[j + s];
        __syncthreads();
    }
    const float denom = sd[0];
    out[b * NH + j] = e / denom;
}

extern "C" void kernel_launch(void* const* d_in, const int* in_sizes, int n_in,
                              void* d_out, int out_size, void* d_ws, size_t ws_size,
                              hipStream_t stream)
{
    const float* td_u = (const float*)d_in[0];
    const float* td_l = (const float*)d_in[1];
    const float* ld_u = (const float*)d_in[2];
    const float* ld_l = (const float*)d_in[3];
    const int*   cloc = (const int*)d_in[4];
    const int*   llen = (const int*)d_in[5];
    const float* Wih  = (const float*)d_in[6];
    const float* Wtu  = (const float*)d_in[7];
    const float* Wtl  = (const float*)d_in[8];
    const float* Wsu  = (const float*)d_in[9];
    const float* Wsl  = (const float*)d_in[10];
    const float* h0   = (const float*)d_in[11];
    const float* locw = (const float*)d_in[12];

    float* S  = (float*)d_ws;              // 4*NH*NB, fully written by k1
    float* Vc = S  + 4 * NH * NB;          // NH*NB
    float* Vd = Vc + NH * NB;              // NH*NB
    float* lg = Vd + NH * NB;              // NB*NH (transposed)
    float* out = (float*)d_out;

    k1_gather<<<dim3(NH / 32, NB), 256, 0, stream>>>(
        td_u, td_l, ld_u, ld_l, cloc, llen, locw, S);
    k2_vt<<<NH / 4, 256, 0, stream>>>(Wtu, Wtl, S, Vc, Vd);
    k3_logits<<<NH / 4, 256, 0, stream>>>(Wsu, Wsl, Wih, h0, Vc, Vd, lg);
    k4_softmax<<<NB, 512, 0, stream>>>(lg, out);
}

// Round 5
// 307.404 us; speedup vs baseline: 1.0753x; 1.0753x over previous
//
#include <hip/hip_runtime.h>
#include <math.h>

// Problem constants (reference: B=64, L=512, H=512, LOC_SIZE=100000)
constexpr int NB = 64;
constexpr int NL = 512;
constexpr int NH = 512;
#define EPSV 1e-9f

// Workspace layout (floats):
//   S   : 4 * NH * NB   (S_t[arr][h][b], arr = {ca, cb, da, db})
//   Vc  : NH * NB       (Vc_t[k][b])
//   Vd  : NH * NB       (Vd_t[k][b])
//   lg  : NH * NB       (logits_t[j][b])
// S/Vc/Vd/lg are FULLY written by their producer kernels (no memset, no atomics).
//
// NOTE (R4 post-mortem): the timed iteration is dominated by harness-side
// traffic (2x 800 MB workspace poison fills @ ~123 us each + ~205 MB input
// restore ~65 us == ~311 us); these four kernels contribute ~0-3 us. The
// R3 configuration below measured 311.05 us total. j-tiling k2/k3 (R4)
// regressed +19.5 us by dropping occupancy 512->128 blocks. Keep 512.

// ---------------------------------------------------------------------------
// K1: masked, coefficient-weighted gather-reduce over L. Atomic-free.
// grid = (NH/32, NB) = (16, 64) blocks, 256 threads.
// Thread (hi = tid&7, ls = tid>>3): h-range hc*32 + hi*4 .. +3, l stride 32.
// Gathers: 8 lanes x float4 = 128 B contiguous per row per l. Register
// accumulate, shuffle-reduce the 8 ls-groups per wave, LDS-combine the
// 4 waves, direct store (each S element owned by exactly one block).
// ---------------------------------------------------------------------------
__global__ __launch_bounds__(256) void k1_gather(
    const float* __restrict__ td_u, const float* __restrict__ td_l,
    const float* __restrict__ ld_u, const float* __restrict__ ld_l,
    const int* __restrict__ cur_loc, const int* __restrict__ loc_len,
    const float* __restrict__ locw, float* __restrict__ S)
{
    const int hc  = blockIdx.x;       // h-chunk: 32 h each
    const int b   = blockIdx.y;
    const int len = loc_len[b];
    const int tid = threadIdx.x;
    const int hi  = tid & 7;          // h-group (4 floats) within chunk
    const int ls  = tid >> 3;         // l-slice 0..31
    const int hbase = hc * 32 + hi * 4;

    float acc[4][4];
#pragma unroll
    for (int a = 0; a < 4; ++a)
#pragma unroll
        for (int e = 0; e < 4; ++e) acc[a][e] = 0.f;

#pragma unroll 4
    for (int l = ls; l < len; l += 32) {
        const int off = b * NL + l;
        const float tu = td_u[off], tl = td_l[off];
        const float lu = ld_u[off], ll = ld_l[off];
        const float rt = 1.f / (tu + tl + EPSV);
        const float rl = 1.f / (lu + ll + EPSV);
        const float a_ = tu * rt, b_ = tl * rt;
        const float c_ = lu * rl, d_ = ll * rl;
        const float w[4] = { c_ * a_, c_ * b_, d_ * a_, d_ * b_ };
        const int idx = cur_loc[off];
        const float4 x = *(const float4*)(locw + (size_t)idx * NH + hbase);
#pragma unroll
        for (int a = 0; a < 4; ++a) {
            acc[a][0] += w[a] * x.x;
            acc[a][1] += w[a] * x.y;
            acc[a][2] += w[a] * x.z;
            acc[a][3] += w[a] * x.w;
        }
    }

    // reduce the 8 ls-groups within each wave (lane stride 8)
#pragma unroll
    for (int a = 0; a < 4; ++a)
#pragma unroll
        for (int e = 0; e < 4; ++e) {
            float x = acc[a][e];
            x += __shfl_down(x, 32);
            x += __shfl_down(x, 16);
            x += __shfl_down(x, 8);
            acc[a][e] = x;
        }

    __shared__ float red[4][8][17];   // [wave][hi][v], padded vs bank conflicts
    const int wv = tid >> 6;
    if ((tid & 63) < 8) {
#pragma unroll
        for (int a = 0; a < 4; ++a)
#pragma unroll
            for (int e = 0; e < 4; ++e) red[wv][hi][a * 4 + e] = acc[a][e];
    }
    __syncthreads();

    if (tid < 128) {
        const int hi2 = tid & 7;
        const int v   = tid >> 3;     // 0..15
        const float s = red[0][hi2][v] + red[1][hi2][v]
                      + red[2][hi2][v] + red[3][hi2][v];
        const int a = v >> 2, e = v & 3;
        S[a * (NH * NB) + (hc * 32 + hi2 * 4 + e) * NB + b] = s;
    }
}

// ---------------------------------------------------------------------------
// K2: Vc_t[j][b] = sum_h Wtu[j,h]*S_ca[h][b] + Wtl[j,h]*S_cb[h][b]
//     Vd_t[j][b] = sum_h Wtu[j,h]*S_da[h][b] + Wtl[j,h]*S_db[h][b]
// One block per j (512 blocks, 8 waves/CU). W rows staged in LDS (coalesced).
// K split across the block's 4 waves (128 h each); lane = b so S reads are
// coalesced 256 B. LDS tree-combine at the end.
// ---------------------------------------------------------------------------
__global__ __launch_bounds__(256) void k2_vt(
    const float* __restrict__ Wtu, const float* __restrict__ Wtl,
    const float* __restrict__ S,
    float* __restrict__ Vc, float* __restrict__ Vd)
{
    const int j   = blockIdx.x;
    const int tid = threadIdx.x;

    __shared__ float wu_s[NH];
    __shared__ float wl_s[NH];
    __shared__ float comb[4][2][NB];

    {
        const float2 va = ((const float2*)(Wtu + (size_t)j * NH))[tid];
        const float2 vb = ((const float2*)(Wtl + (size_t)j * NH))[tid];
        ((float2*)wu_s)[tid] = va;
        ((float2*)wl_s)[tid] = vb;
    }
    __syncthreads();

    const int w    = tid >> 6;
    const int lane = tid & 63;
    const float* __restrict__ Sca = S;
    const float* __restrict__ Scb = S + NH * NB;
    const float* __restrict__ Sda = S + 2 * NH * NB;
    const float* __restrict__ Sdb = S + 3 * NH * NB;

    float vc0 = 0.f, vc1 = 0.f, vd0 = 0.f, vd1 = 0.f;
    const int hbeg = w * 128;
#pragma unroll 8
    for (int h = hbeg; h < hbeg + 128; h += 2) {
        const float wuA = wu_s[h],     wlA = wl_s[h];
        const float wuB = wu_s[h + 1], wlB = wl_s[h + 1];
        const int oA = h * NB + lane;
        const int oB = oA + NB;
        vc0 += wuA * Sca[oA] + wlA * Scb[oA];
        vd0 += wuA * Sda[oA] + wlA * Sdb[oA];
        vc1 += wuB * Sca[oB] + wlB * Scb[oB];
        vd1 += wuB * Sda[oB] + wlB * Sdb[oB];
    }
    comb[w][0][lane] = vc0 + vc1;
    comb[w][1][lane] = vd0 + vd1;
    __syncthreads();

    if (tid < NB) {
        Vc[j * NB + tid] = comb[0][0][tid] + comb[1][0][tid]
                         + comb[2][0][tid] + comb[3][0][tid];
    } else if (tid < 2 * NB) {
        const int ln = tid - NB;
        Vd[j * NB + ln] = comb[0][1][ln] + comb[1][1][ln]
                        + comb[2][1][ln] + comb[3][1][ln];
    }
}

// ---------------------------------------------------------------------------
// K3: lg_t[j][b] = sum_k Wsu[j,k]*Vc[k][b] + Wsl[j,k]*Vd[k][b] + usr[j]
//     usr[j] = sum_k Wih[j,k]*h0[k], folded into the same K-split loop.
// ---------------------------------------------------------------------------
__global__ __launch_bounds__(256) void k3_logits(
    const float* __restrict__ Wsu, const float* __restrict__ Wsl,
    const float* __restrict__ Wih, const float* __restrict__ h0p,
    const float* __restrict__ Vc, const float* __restrict__ Vd,
    float* __restrict__ lg)
{
    const int j   = blockIdx.x;
    const int tid = threadIdx.x;

    __shared__ float su_s[NH];
    __shared__ float sl_s[NH];
    __shared__ float ih_s[NH];
    __shared__ float h0_s[NH];
    __shared__ float comb[4][64];
    __shared__ float comb_u[4];

    {
        const float2 va = ((const float2*)(Wsu + (size_t)j * NH))[tid];
        const float2 vb = ((const float2*)(Wsl + (size_t)j * NH))[tid];
        const float2 vi = ((const float2*)(Wih + (size_t)j * NH))[tid];
        const float2 vh = ((const float2*)h0p)[tid];
        ((float2*)su_s)[tid] = va;
        ((float2*)sl_s)[tid] = vb;
        ((float2*)ih_s)[tid] = vi;
        ((float2*)h0_s)[tid] = vh;
    }
    __syncthreads();

    const int w    = tid >> 6;
    const int lane = tid & 63;

    float s0 = 0.f, s1 = 0.f, u = 0.f;
    const int kbeg = w * 128;
#pragma unroll 8
    for (int k = kbeg; k < kbeg + 128; k += 2) {
        const float aA = su_s[k],     cA = sl_s[k];
        const float aB = su_s[k + 1], cB = sl_s[k + 1];
        const int oA = k * NB + lane;
        const int oB = oA + NB;
        s0 += aA * Vc[oA] + cA * Vd[oA];
        s1 += aB * Vc[oB] + cB * Vd[oB];
        u  += ih_s[k] * h0_s[k] + ih_s[k + 1] * h0_s[k + 1];
    }
    comb[w][lane] = s0 + s1;
    if (lane == 0) comb_u[w] = u;
    __syncthreads();

    if (tid < NB) {
        const float s = comb[0][tid] + comb[1][tid] + comb[2][tid] + comb[3][tid];
        const float usr = comb_u[0] + comb_u[1] + comb_u[2] + comb_u[3];
        lg[j * NB + tid] = s + usr;
    }
}

// ---------------------------------------------------------------------------
// K4: per-batch softmax over H. grid = NB, block = 512 (thread j).
// ---------------------------------------------------------------------------
__global__ __launch_bounds__(512) void k4_softmax(
    const float* __restrict__ lg, float* __restrict__ out)
{
    const int b = blockIdx.x;
    const int j = threadIdx.x;
    __shared__ float sd[512];

    const float v = lg[j * NB + b];
    sd[j] = v;
    __syncthreads();
    for (int s = 256; s > 0; s >>= 1) {
        if (j < s) sd[j] = fmaxf(sd[j], sd[j + s]);
        __syncthreads();
    }
    const float m = sd[0];
    __syncthreads();
    const float e = expf(v - m);
    sd[j] = e;
    __syncthreads();
    for (int s = 256; s > 0; s >>= 1) {
        if (j < s) sd[j] += sd[j + s];
        __syncthreads();
    }
    const float denom = sd[0];
    out[b * NH + j] = e / denom;
}

extern "C" void kernel_launch(void* const* d_in, const int* in_sizes, int n_in,
                              void* d_out, int out_size, void* d_ws, size_t ws_size,
                              hipStream_t stream)
{
    const float* td_u = (const float*)d_in[0];
    const float* td_l = (const float*)d_in[1];
    const float* ld_u = (const float*)d_in[2];
    const float* ld_l = (const float*)d_in[3];
    const int*   cloc = (const int*)d_in[4];
    const int*   llen = (const int*)d_in[5];
    const float* Wih  = (const float*)d_in[6];
    const float* Wtu  = (const float*)d_in[7];
    const float* Wtl  = (const float*)d_in[8];
    const float* Wsu  = (const float*)d_in[9];
    const float* Wsl  = (const float*)d_in[10];
    const float* h0   = (const float*)d_in[11];
    const float* locw = (const float*)d_in[12];

    float* S  = (float*)d_ws;              // 4*NH*NB, fully written by k1
    float* Vc = S  + 4 * NH * NB;          // NH*NB
    float* Vd = Vc + NH * NB;              // NH*NB
    float* lg = Vd + NH * NB;              // NH*NB
    float* out = (float*)d_out;

    k1_gather<<<dim3(NH / 32, NB), 256, 0, stream>>>(
        td_u, td_l, ld_u, ld_l, cloc, llen, locw, S);
    k2_vt<<<NH, 256, 0, stream>>>(Wtu, Wtl, S, Vc, Vd);
    k3_logits<<<NH, 256, 0, stream>>>(Wsu, Wsl, Wih, h0, Vc, Vd, lg);
    k4_softmax<<<NB, 512, 0, stream>>>(lg, out);
}